// Round 7
// baseline (320.018 us; speedup 1.0000x reference)
//
#include <hip/hip_runtime.h>
#include <math.h>

#define N_NODES 50000
#define N_EDGES 600000
#define D 128
#define BN_EPS 1e-5f
#define ELLW 64

typedef float f32x4 __attribute__((ext_vector_type(4)));
typedef short short8 __attribute__((ext_vector_type(8)));

__device__ __forceinline__ unsigned short f2bf(float f) {
    unsigned int x = __float_as_uint(f);
    return (unsigned short)((x + 0x7FFFu + ((x >> 16) & 1u)) >> 16);  // RNE
}

// ---------------- init: cur = 0 (ELL cursors), stats = 0 ----------------
__global__ void init_kernel(int* __restrict__ cur, float* __restrict__ stats) {
    int i = blockIdx.x * blockDim.x + threadIdx.x;
    if (i < N_NODES) cur[i] = 0;
    if (i < 4 * D) stats[i] = 0.0f;
}

// ---------------- transpose + bf16-cast both weight matrices ----------------
// WT[col][k] = bf16(W[k][col]); 16384 threads
__global__ void prep_kernel(const float* __restrict__ W1, const float* __restrict__ W2,
                            unsigned short* __restrict__ WT1, unsigned short* __restrict__ WT2) {
    int idx = blockIdx.x * blockDim.x + threadIdx.x;
    if (idx >= D * D) return;
    int col = idx >> 7, k = idx & 127;
    WT1[col * D + k] = f2bf(W1[k * D + col]);
    WT2[col * D + k] = f2bf(W2[k * D + col]);
}

// ---------------- build ELL adjacency: dst -> list of src (int) ----------------
__global__ void scatter_kernel(const int* __restrict__ srcI, const int* __restrict__ dstI,
                               int* __restrict__ cur, int* __restrict__ ell) {
    int e = blockIdx.x * blockDim.x + threadIdx.x;
    if (e >= N_EDGES) return;
    int d = dstI[e];
    int pos = atomicAdd(&cur[d], 1);
    if (pos < ELLW) ell[(size_t)d * ELLW + pos] = srcI[e];
}

// ---------------- dinv = rsqrt(in_degree + 1)  (self-loop) ----------------
__global__ void dinv_kernel(const int* __restrict__ cur, float* __restrict__ dinv) {
    int i = blockIdx.x * blockDim.x + threadIdx.x;
    if (i < N_NODES) dinv[i] = rsqrtf((float)cur[i] + 1.0f);
}

// ---------------- MFMA GEMM: C = act(A) @ WT^T (+bias) [+fused col stats] ----------------
// A: [M x 128] f32 (read once per block, cast bf16 in regs)
// WT: [128 cols][128 k] bf16 (pre-transposed weight; L1-resident, re-read per wave)
// Block: 256 thr = 4 waves; wave w owns rows [blk*128 + w*32, +32); acc 2x8 f32x4.
// BN: a -> relu(a*scale[k]+bias[k]) in f32 before bf16 cast (scale/bias from raw stats).
template<bool BN, bool HAS_BIAS, bool STATS>
__global__ __launch_bounds__(256) void gemm_mfma_kernel(
    const float* __restrict__ A, const unsigned short* __restrict__ WT,
    const float* __restrict__ bn_sum, const float* __restrict__ bn_sq,
    const float* __restrict__ bn_gamma, const float* __restrict__ bn_beta,
    const float* __restrict__ out_bias, float* __restrict__ C, int M,
    float* __restrict__ sum_out, float* __restrict__ sq_out)
{
    __shared__ __align__(16) float scs[D];
    __shared__ __align__(16) float bis[D];
    __shared__ float ssum[D];
    __shared__ float ssq[D];

    const int tid  = threadIdx.x;
    const int lane = tid & 63;
    const int w    = tid >> 6;
    const int l15  = lane & 15;
    const int lg   = lane >> 4;

    if (BN) {
        if (tid < D) {
            const float inv_n = 1.0f / (float)N_NODES;
            float mean = bn_sum[tid] * inv_n;
            float var  = bn_sq[tid] * inv_n - mean * mean;
            float rstd = rsqrtf(var + BN_EPS);
            float sc = bn_gamma[tid] * rstd;
            scs[tid] = sc;
            bis[tid] = bn_beta[tid] - mean * sc;
        }
    }
    if (STATS) {
        if (tid < D) { ssum[tid] = 0.f; ssq[tid] = 0.f; }
    }
    if (BN || STATS) __syncthreads();

    const int rbase = blockIdx.x * 128 + w * 32;
    int ar0 = rbase + l15;      if (ar0 > M - 1) ar0 = M - 1;
    int ar1 = rbase + 16 + l15; if (ar1 > M - 1) ar1 = M - 1;

    f32x4 acc[2][8];
    #pragma unroll
    for (int rt = 0; rt < 2; ++rt)
        #pragma unroll
        for (int ct = 0; ct < 8; ++ct) acc[rt][ct] = (f32x4){0.f, 0.f, 0.f, 0.f};

    #pragma unroll
    for (int ks = 0; ks < 4; ++ks) {
        const int kb = ks * 32 + lg * 8;
        short8 afr[2];
        #pragma unroll
        for (int rt = 0; rt < 2; ++rt) {
            const float* ap = &A[(size_t)(rt ? ar1 : ar0) * D + kb];
            float4 v0 = *(const float4*)ap;
            float4 v1 = *(const float4*)(ap + 4);
            float vv[8] = {v0.x, v0.y, v0.z, v0.w, v1.x, v1.y, v1.z, v1.w};
            short8 af;
            #pragma unroll
            for (int j = 0; j < 8; ++j) {
                float f = vv[j];
                if (BN) f = fmaxf(fmaf(f, scs[kb + j], bis[kb + j]), 0.f);
                af[j] = (short)f2bf(f);
            }
            afr[rt] = af;
        }
        #pragma unroll
        for (int ct = 0; ct < 8; ++ct) {
            short8 bfr = *(const short8*)&WT[(ct * 16 + l15) * D + kb];
            acc[0][ct] = __builtin_amdgcn_mfma_f32_16x16x32_bf16(afr[0], bfr, acc[0][ct], 0, 0, 0);
            acc[1][ct] = __builtin_amdgcn_mfma_f32_16x16x32_bf16(afr[1], bfr, acc[1][ct], 0, 0, 0);
        }
    }

    float ob[8];
    #pragma unroll
    for (int ct = 0; ct < 8; ++ct) ob[ct] = HAS_BIAS ? out_bias[ct * 16 + l15] : 0.f;

    float psum[8], psq[8];
    #pragma unroll
    for (int ct = 0; ct < 8; ++ct) { psum[ct] = 0.f; psq[ct] = 0.f; }

    // C/D layout (m89-verified): col = ct*16 + (lane&15), row = rbase + rt*16 + (lane>>4)*4 + j
    #pragma unroll
    for (int rt = 0; rt < 2; ++rt) {
        const int rb2 = rbase + rt * 16 + lg * 4;
        #pragma unroll
        for (int j = 0; j < 4; ++j) {
            const int row = rb2 + j;
            if (row < M) {
                #pragma unroll
                for (int ct = 0; ct < 8; ++ct) {
                    float o = acc[rt][ct][j] + ob[ct];
                    C[(size_t)row * D + ct * 16 + l15] = o;
                    if (STATS) { psum[ct] += o; psq[ct] = fmaf(o, o, psq[ct]); }
                }
            }
        }
    }

    if (STATS) {
        #pragma unroll
        for (int ct = 0; ct < 8; ++ct) {
            atomicAdd(&ssum[ct * 16 + l15], psum[ct]);
            atomicAdd(&ssq[ct * 16 + l15], psq[ct]);
        }
        __syncthreads();
        if (tid < D) {
            unsafeAtomicAdd(&sum_out[tid], ssum[tid]);
            unsafeAtomicAdd(&sq_out[tid], ssq[tid]);
        }
    }
}

// ---------------- gather: out = dinv[d]*(sum_s dinv[s]*h2[s] + dinv[d]*h2[d]) + b_conv
//   one wave per node; lane l handles cols {2l, 2l+1}; fused BN2 stats
//   (R2-proven structure; grid 2048 for occupancy)
__global__ __launch_bounds__(256) void gather_kernel(
    const int* __restrict__ ell, const int* __restrict__ cnt,
    const float* __restrict__ dinv, const float* __restrict__ h2,
    const float* __restrict__ b_conv, float* __restrict__ outpre,
    float* __restrict__ sum_out, float* __restrict__ sq_out)
{
    const int lane = threadIdx.x & 63;
    const int wid  = threadIdx.x >> 6;
    const float2 bc = *(const float2*)&b_conv[lane * 2];
    float2 sum = make_float2(0.f, 0.f);
    float2 sq  = make_float2(0.f, 0.f);

    for (int d = blockIdx.x * 4 + wid; d < N_NODES; d += gridDim.x * 4) {
        int c = cnt[d]; if (c > ELLW) c = ELLW;
        const float dd = dinv[d];
        float2 hv = *(const float2*)&h2[(size_t)d * D + lane * 2];
        float2 acc;
        acc.x = dd * hv.x;
        acc.y = dd * hv.y;
        const int base = d * ELLW;
        int j = 0;
        for (; j + 1 < c; j += 2) {
            int s0 = ell[base + j];
            int s1 = ell[base + j + 1];
            float w0 = dinv[s0];
            float w1 = dinv[s1];
            float2 v0 = *(const float2*)&h2[(size_t)s0 * D + lane * 2];
            float2 v1 = *(const float2*)&h2[(size_t)s1 * D + lane * 2];
            acc.x += w0 * v0.x + w1 * v1.x;
            acc.y += w0 * v0.y + w1 * v1.y;
        }
        if (j < c) {
            int s0 = ell[base + j];
            float w0 = dinv[s0];
            float2 v0 = *(const float2*)&h2[(size_t)s0 * D + lane * 2];
            acc.x += w0 * v0.x;
            acc.y += w0 * v0.y;
        }
        float2 o;
        o.x = fmaf(dd, acc.x, bc.x);
        o.y = fmaf(dd, acc.y, bc.y);
        *(float2*)&outpre[(size_t)d * D + lane * 2] = o;
        sum.x += o.x; sum.y += o.y;
        sq.x = fmaf(o.x, o.x, sq.x);
        sq.y = fmaf(o.y, o.y, sq.y);
    }

    __shared__ float2 sS[256];
    __shared__ float2 qS[256];
    sS[threadIdx.x] = sum; qS[threadIdx.x] = sq;
    __syncthreads();
    if (wid == 0) {
        #pragma unroll
        for (int w = 1; w < 4; ++w) {
            float2 s2 = sS[w * 64 + lane];
            float2 q2 = qS[w * 64 + lane];
            sum.x += s2.x; sum.y += s2.y;
            sq.x += q2.x; sq.y += q2.y;
        }
        unsafeAtomicAdd(&sum_out[lane * 2 + 0], sum.x);
        unsafeAtomicAdd(&sum_out[lane * 2 + 1], sum.y);
        unsafeAtomicAdd(&sq_out[lane * 2 + 0], sq.x);
        unsafeAtomicAdd(&sq_out[lane * 2 + 1], sq.y);
    }
}

// ---------------- final: out = relu(out*scale2 + bias2), scale/bias from raw stats ----------------
__global__ void final_kernel(float* __restrict__ out,
        const float* __restrict__ s_sum, const float* __restrict__ s_sq,
        const float* __restrict__ gamma, const float* __restrict__ beta) {
    __shared__ __align__(16) float scs[D];
    __shared__ __align__(16) float bis[D];
    const int tid = threadIdx.x;
    if (tid < D) {
        const float inv_n = 1.0f / (float)N_NODES;
        float mean = s_sum[tid] * inv_n;
        float var  = s_sq[tid] * inv_n - mean * mean;
        float rstd = rsqrtf(var + BN_EPS);
        float sc = gamma[tid] * rstd;
        scs[tid] = sc;
        bis[tid] = beta[tid] - mean * sc;
    }
    __syncthreads();
    const int t = blockIdx.x * blockDim.x + tid;
    const int c4 = t & 31;
    float4 sc = *(const float4*)&scs[c4 * 4];
    float4 bi = *(const float4*)&bis[c4 * 4];
    const int total = N_NODES * D / 4;
    const int stride = gridDim.x * blockDim.x;
    for (int i = t; i < total; i += stride) {
        float4 v = ((const float4*)out)[i];
        v.x = fmaxf(fmaf(v.x, sc.x, bi.x), 0.f);
        v.y = fmaxf(fmaf(v.y, sc.y, bi.y), 0.f);
        v.z = fmaxf(fmaf(v.z, sc.z, bi.z), 0.f);
        v.w = fmaxf(fmaf(v.w, sc.w, bi.w), 0.f);
        ((float4*)out)[i] = v;
    }
}

extern "C" void kernel_launch(void* const* d_in, const int* in_sizes, int n_in,
                              void* d_out, int out_size, void* d_ws, size_t ws_size,
                              hipStream_t stream) {
    const float* x      = (const float*)d_in[0];
    const int*   edge   = (const int*)d_in[1];      // [2][N_EDGES], row0=src, row1=dst
    const float* W_mlp  = (const float*)d_in[2];
    const float* b_mlp  = (const float*)d_in[3];
    const float* gamma1 = (const float*)d_in[4];
    const float* beta1  = (const float*)d_in[5];
    const float* W_conv = (const float*)d_in[6];
    const float* b_conv = (const float*)d_in[7];
    const float* gamma2 = (const float*)d_in[8];
    const float* beta2  = (const float*)d_in[9];
    float* out = (float*)d_out;

    float* ws = (float*)d_ws;
    float* h1   = ws;                                  // N*D floats (25.6 MB)
    float* h2   = ws + (size_t)N_NODES * D;            // N*D floats
    int*   ell  = (int*)h1;                            // alias: h1 dead after gemm2 (12.8MB)
    float* extra = ws + 2 * (size_t)N_NODES * D;
    int*   cur  = (int*)extra;                         // N ints (ELL cursors / in-degree)
    float* dinv = extra + N_NODES;                     // N floats
    float* stats = extra + 2 * N_NODES;                // 4*D
    float* sum1 = stats;         float* sq1 = stats + D;
    float* sum2 = stats + 2 * D; float* sq2 = stats + 3 * D;
    unsigned short* WT1 = (unsigned short*)(stats + 4 * D);   // 128*128 bf16
    unsigned short* WT2 = WT1 + D * D;

    const int* srcI = edge;
    const int* dstI = edge + N_EDGES;

    init_kernel<<<(N_NODES + 255) / 256, 256, 0, stream>>>(cur, stats);
    prep_kernel<<<(D * D + 255) / 256, 256, 0, stream>>>(W_mlp, W_conv, WT1, WT2);

    gemm_mfma_kernel<false, true, true><<<(N_NODES + 127) / 128, 256, 0, stream>>>(
        x, WT1, nullptr, nullptr, nullptr, nullptr, b_mlp, h1, N_NODES, sum1, sq1);

    gemm_mfma_kernel<true, false, false><<<(N_NODES + 127) / 128, 256, 0, stream>>>(
        h1, WT2, sum1, sq1, gamma1, beta1, nullptr, h2, N_NODES, nullptr, nullptr);

    // h1 is dead now: build src ELL in its place
    scatter_kernel<<<(N_EDGES + 255) / 256, 256, 0, stream>>>(srcI, dstI, cur, ell);
    dinv_kernel<<<(N_NODES + 255) / 256, 256, 0, stream>>>(cur, dinv);

    gather_kernel<<<2048, 256, 0, stream>>>(ell, cur, dinv, h2, b_conv, out, sum2, sq2);

    final_kernel<<<2048, 256, 0, stream>>>(out, sum2, sq2, gamma2, beta2);
}

// Round 8
// 309.290 us; speedup vs baseline: 1.0347x; 1.0347x over previous
//
#include <hip/hip_runtime.h>
#include <math.h>

#define N_NODES 50000
#define N_EDGES 600000
#define D 128
#define BN_EPS 1e-5f
#define ELLW 64

typedef float f32x4 __attribute__((ext_vector_type(4)));
typedef short short8 __attribute__((ext_vector_type(8)));

__device__ __forceinline__ unsigned short f2bf(float f) {
    unsigned int x = __float_as_uint(f);
    return (unsigned short)((x + 0x7FFFu + ((x >> 16) & 1u)) >> 16);  // RNE
}

// ---------------- init: cur = 0 (ELL cursors), stats = 0 ----------------
__global__ void init_kernel(int* __restrict__ cur, float* __restrict__ stats) {
    int i = blockIdx.x * blockDim.x + threadIdx.x;
    if (i < N_NODES) cur[i] = 0;
    if (i < 4 * D) stats[i] = 0.0f;
}

// ---------------- transpose + bf16-cast both weight matrices ----------------
__global__ void prep_kernel(const float* __restrict__ W1, const float* __restrict__ W2,
                            unsigned short* __restrict__ WT1, unsigned short* __restrict__ WT2) {
    int idx = blockIdx.x * blockDim.x + threadIdx.x;
    if (idx >= D * D) return;
    int col = idx >> 7, k = idx & 127;
    WT1[col * D + k] = f2bf(W1[k * D + col]);
    WT2[col * D + k] = f2bf(W2[k * D + col]);
}

// ---------------- build ELL adjacency: dst -> list of src (int) ----------------
__global__ void scatter_kernel(const int* __restrict__ srcI, const int* __restrict__ dstI,
                               int* __restrict__ cur, int* __restrict__ ell) {
    int e = blockIdx.x * blockDim.x + threadIdx.x;
    if (e >= N_EDGES) return;
    int d = dstI[e];
    int pos = atomicAdd(&cur[d], 1);
    if (pos < ELLW) ell[(size_t)d * ELLW + pos] = srcI[e];
}

// ---------------- dinv = rsqrt(in_degree + 1)  (self-loop) ----------------
__global__ void dinv_kernel(const int* __restrict__ cur, float* __restrict__ dinv) {
    int i = blockIdx.x * blockDim.x + threadIdx.x;
    if (i < N_NODES) dinv[i] = rsqrtf((float)cur[i] + 1.0f);
}

// ---------------- MFMA GEMM: C = act(A) @ WT^T (+bias) [+fused col stats] ----------------
// Block 256 thr = 4 waves; block covers 32 rows. Wave w: rows blk*32+(w&1)*16, cols (w>>1)*64.
// 16 rows x 64 cols per wave -> 6250 waves (~24/CU) for latency hiding. acc = 4 x f32x4.
template<bool BN, bool HAS_BIAS, bool STATS>
__global__ __launch_bounds__(256) void gemm_mfma_kernel(
    const float* __restrict__ A, const unsigned short* __restrict__ WT,
    const float* __restrict__ bn_sum, const float* __restrict__ bn_sq,
    const float* __restrict__ bn_gamma, const float* __restrict__ bn_beta,
    const float* __restrict__ out_bias, float* __restrict__ C, int M,
    float* __restrict__ sum_out, float* __restrict__ sq_out)
{
    __shared__ __align__(16) float scs[D];
    __shared__ __align__(16) float bis[D];
    __shared__ float ssum[D];
    __shared__ float ssq[D];

    const int tid  = threadIdx.x;
    const int lane = tid & 63;
    const int w    = tid >> 6;
    const int l15  = lane & 15;
    const int lg   = lane >> 4;

    if (BN) {
        if (tid < D) {
            const float inv_n = 1.0f / (float)N_NODES;
            float mean = bn_sum[tid] * inv_n;
            float var  = bn_sq[tid] * inv_n - mean * mean;
            float rstd = rsqrtf(var + BN_EPS);
            float sc = bn_gamma[tid] * rstd;
            scs[tid] = sc;
            bis[tid] = bn_beta[tid] - mean * sc;
        }
    }
    if (STATS) {
        if (tid < D) { ssum[tid] = 0.f; ssq[tid] = 0.f; }
    }
    if (BN || STATS) __syncthreads();

    const int rowbase = blockIdx.x * 32 + (w & 1) * 16;
    const int colbase = (w >> 1) * 64;
    int ar = rowbase + l15; if (ar > M - 1) ar = M - 1;

    f32x4 acc[4];
    #pragma unroll
    for (int ct = 0; ct < 4; ++ct) acc[ct] = (f32x4){0.f, 0.f, 0.f, 0.f};

    #pragma unroll
    for (int ks = 0; ks < 4; ++ks) {
        const int kb = ks * 32 + lg * 8;
        const float* ap = &A[(size_t)ar * D + kb];
        float4 v0 = *(const float4*)ap;
        float4 v1 = *(const float4*)(ap + 4);
        float vv[8] = {v0.x, v0.y, v0.z, v0.w, v1.x, v1.y, v1.z, v1.w};
        short8 af;
        #pragma unroll
        for (int j = 0; j < 8; ++j) {
            float f = vv[j];
            if (BN) f = fmaxf(fmaf(f, scs[kb + j], bis[kb + j]), 0.f);
            af[j] = (short)f2bf(f);
        }
        #pragma unroll
        for (int ct = 0; ct < 4; ++ct) {
            short8 bfr = *(const short8*)&WT[(size_t)(colbase + ct * 16 + l15) * D + kb];
            acc[ct] = __builtin_amdgcn_mfma_f32_16x16x32_bf16(af, bfr, acc[ct], 0, 0, 0);
        }
    }

    float ob[4];
    #pragma unroll
    for (int ct = 0; ct < 4; ++ct) ob[ct] = HAS_BIAS ? out_bias[colbase + ct * 16 + l15] : 0.f;

    float psum[4], psq[4];
    #pragma unroll
    for (int ct = 0; ct < 4; ++ct) { psum[ct] = 0.f; psq[ct] = 0.f; }

    // C/D layout: col = colbase + ct*16 + (lane&15), row = rowbase + (lane>>4)*4 + j
    const int rb2 = rowbase + lg * 4;
    #pragma unroll
    for (int j = 0; j < 4; ++j) {
        const int row = rb2 + j;
        if (row < M) {
            #pragma unroll
            for (int ct = 0; ct < 4; ++ct) {
                float o = acc[ct][j] + ob[ct];
                C[(size_t)row * D + colbase + ct * 16 + l15] = o;
                if (STATS) { psum[ct] += o; psq[ct] = fmaf(o, o, psq[ct]); }
            }
        }
    }

    if (STATS) {
        #pragma unroll
        for (int ct = 0; ct < 4; ++ct) {
            atomicAdd(&ssum[colbase + ct * 16 + l15], psum[ct]);
            atomicAdd(&ssq[colbase + ct * 16 + l15], psq[ct]);
        }
        __syncthreads();
        if (tid < D) {
            unsafeAtomicAdd(&sum_out[tid], ssum[tid]);
            unsafeAtomicAdd(&sq_out[tid], ssq[tid]);
        }
    }
}

// ---------------- gather: out = dinv[d]*(sum_s dinv[s]*h2[s] + dinv[d]*h2[d]) + b_conv
//   one wave per node; lane l handles cols {2l,2l+1}; fused BN2 stats.
//   Edge indices/weights loaded ONCE per wave (lane-parallel), then broadcast
//   via __shfl so the h2-row loads have no memory-dependency between them.
__global__ __launch_bounds__(256) void gather_kernel(
    const int* __restrict__ ell, const int* __restrict__ cnt,
    const float* __restrict__ dinv, const float* __restrict__ h2,
    const float* __restrict__ b_conv, float* __restrict__ outpre,
    float* __restrict__ sum_out, float* __restrict__ sq_out)
{
    const int lane = threadIdx.x & 63;
    const int wid  = threadIdx.x >> 6;
    const int col  = lane * 2;
    const float2 bc = *(const float2*)&b_conv[col];
    float2 sum = make_float2(0.f, 0.f);
    float2 sq  = make_float2(0.f, 0.f);

    for (int d = blockIdx.x * 4 + wid; d < N_NODES; d += gridDim.x * 4) {
        int c = cnt[d]; if (c > ELLW) c = ELLW;
        const float dd = dinv[d];
        float2 hv = *(const float2*)&h2[(size_t)d * D + col];
        float2 acc;
        acc.x = dd * hv.x;
        acc.y = dd * hv.y;
        const int base = d * ELLW;
        int   sl = 0;
        float wl = 0.f;
        if (lane < c) {
            sl = ell[base + lane];     // coalesced: one 256B row load
            wl = dinv[sl];             // one gather (≤c active lanes)
        }
        int j = 0;
        for (; j + 4 <= c; j += 4) {
            int s0 = __shfl(sl, j);     int s1 = __shfl(sl, j + 1);
            int s2 = __shfl(sl, j + 2); int s3 = __shfl(sl, j + 3);
            float w0 = __shfl(wl, j);     float w1 = __shfl(wl, j + 1);
            float w2 = __shfl(wl, j + 2); float w3 = __shfl(wl, j + 3);
            float2 v0 = *(const float2*)&h2[(size_t)s0 * D + col];
            float2 v1 = *(const float2*)&h2[(size_t)s1 * D + col];
            float2 v2 = *(const float2*)&h2[(size_t)s2 * D + col];
            float2 v3 = *(const float2*)&h2[(size_t)s3 * D + col];
            acc.x += w0 * v0.x + w1 * v1.x + w2 * v2.x + w3 * v3.x;
            acc.y += w0 * v0.y + w1 * v1.y + w2 * v2.y + w3 * v3.y;
        }
        for (; j < c; ++j) {
            int s = __shfl(sl, j);
            float ww = __shfl(wl, j);
            float2 v = *(const float2*)&h2[(size_t)s * D + col];
            acc.x = fmaf(ww, v.x, acc.x);
            acc.y = fmaf(ww, v.y, acc.y);
        }
        float2 o;
        o.x = fmaf(dd, acc.x, bc.x);
        o.y = fmaf(dd, acc.y, bc.y);
        *(float2*)&outpre[(size_t)d * D + col] = o;
        sum.x += o.x; sum.y += o.y;
        sq.x = fmaf(o.x, o.x, sq.x);
        sq.y = fmaf(o.y, o.y, sq.y);
    }

    __shared__ float2 sS[256];
    __shared__ float2 qS[256];
    sS[threadIdx.x] = sum; qS[threadIdx.x] = sq;
    __syncthreads();
    if (wid == 0) {
        #pragma unroll
        for (int w = 1; w < 4; ++w) {
            float2 s2 = sS[w * 64 + lane];
            float2 q2 = qS[w * 64 + lane];
            sum.x += s2.x; sum.y += s2.y;
            sq.x += q2.x; sq.y += q2.y;
        }
        unsafeAtomicAdd(&sum_out[col + 0], sum.x);
        unsafeAtomicAdd(&sum_out[col + 1], sum.y);
        unsafeAtomicAdd(&sq_out[col + 0], sq.x);
        unsafeAtomicAdd(&sq_out[col + 1], sq.y);
    }
}

// ---------------- final: out = relu(out*scale2 + bias2), scale/bias from raw stats ----------------
__global__ void final_kernel(float* __restrict__ out,
        const float* __restrict__ s_sum, const float* __restrict__ s_sq,
        const float* __restrict__ gamma, const float* __restrict__ beta) {
    __shared__ __align__(16) float scs[D];
    __shared__ __align__(16) float bis[D];
    const int tid = threadIdx.x;
    if (tid < D) {
        const float inv_n = 1.0f / (float)N_NODES;
        float mean = s_sum[tid] * inv_n;
        float var  = s_sq[tid] * inv_n - mean * mean;
        float rstd = rsqrtf(var + BN_EPS);
        float sc = gamma[tid] * rstd;
        scs[tid] = sc;
        bis[tid] = beta[tid] - mean * sc;
    }
    __syncthreads();
    const int t = blockIdx.x * blockDim.x + tid;
    const int c4 = t & 31;
    float4 sc = *(const float4*)&scs[c4 * 4];
    float4 bi = *(const float4*)&bis[c4 * 4];
    const int total = N_NODES * D / 4;
    const int stride = gridDim.x * blockDim.x;
    for (int i = t; i < total; i += stride) {
        float4 v = ((const float4*)out)[i];
        v.x = fmaxf(fmaf(v.x, sc.x, bi.x), 0.f);
        v.y = fmaxf(fmaf(v.y, sc.y, bi.y), 0.f);
        v.z = fmaxf(fmaf(v.z, sc.z, bi.z), 0.f);
        v.w = fmaxf(fmaf(v.w, sc.w, bi.w), 0.f);
        ((float4*)out)[i] = v;
    }
}

extern "C" void kernel_launch(void* const* d_in, const int* in_sizes, int n_in,
                              void* d_out, int out_size, void* d_ws, size_t ws_size,
                              hipStream_t stream) {
    const float* x      = (const float*)d_in[0];
    const int*   edge   = (const int*)d_in[1];      // [2][N_EDGES], row0=src, row1=dst
    const float* W_mlp  = (const float*)d_in[2];
    const float* b_mlp  = (const float*)d_in[3];
    const float* gamma1 = (const float*)d_in[4];
    const float* beta1  = (const float*)d_in[5];
    const float* W_conv = (const float*)d_in[6];
    const float* b_conv = (const float*)d_in[7];
    const float* gamma2 = (const float*)d_in[8];
    const float* beta2  = (const float*)d_in[9];
    float* out = (float*)d_out;

    float* ws = (float*)d_ws;
    float* h1   = ws;                                  // N*D floats (25.6 MB)
    float* h2   = ws + (size_t)N_NODES * D;            // N*D floats
    int*   ell  = (int*)h1;                            // alias: h1 dead after gemm2 (12.8MB)
    float* extra = ws + 2 * (size_t)N_NODES * D;
    int*   cur  = (int*)extra;                         // N ints (ELL cursors / in-degree)
    float* dinv = extra + N_NODES;                     // N floats
    float* stats = extra + 2 * N_NODES;                // 4*D
    float* sum1 = stats;         float* sq1 = stats + D;
    float* sum2 = stats + 2 * D; float* sq2 = stats + 3 * D;
    unsigned short* WT1 = (unsigned short*)(stats + 4 * D);   // 128*128 bf16
    unsigned short* WT2 = WT1 + D * D;

    const int* srcI = edge;
    const int* dstI = edge + N_EDGES;

    init_kernel<<<(N_NODES + 255) / 256, 256, 0, stream>>>(cur, stats);
    prep_kernel<<<(D * D + 255) / 256, 256, 0, stream>>>(W_mlp, W_conv, WT1, WT2);

    gemm_mfma_kernel<false, true, true><<<(N_NODES + 31) / 32, 256, 0, stream>>>(
        x, WT1, nullptr, nullptr, nullptr, nullptr, b_mlp, h1, N_NODES, sum1, sq1);

    gemm_mfma_kernel<true, false, false><<<(N_NODES + 31) / 32, 256, 0, stream>>>(
        h1, WT2, sum1, sq1, gamma1, beta1, nullptr, h2, N_NODES, nullptr, nullptr);

    // h1 is dead now: build src ELL in its place
    scatter_kernel<<<(N_EDGES + 255) / 256, 256, 0, stream>>>(srcI, dstI, cur, ell);
    dinv_kernel<<<(N_NODES + 255) / 256, 256, 0, stream>>>(cur, dinv);

    gather_kernel<<<1024, 256, 0, stream>>>(ell, cur, dinv, h2, b_conv, out, sum2, sq2);

    final_kernel<<<2048, 256, 0, stream>>>(out, sum2, sq2, gamma2, beta2);
}

// Round 9
// 270.200 us; speedup vs baseline: 1.1844x; 1.1447x over previous
//
#include <hip/hip_runtime.h>
#include <math.h>

#define N_NODES 50000
#define N_EDGES 600000
#define D 128
#define BN_EPS 1e-5f
#define ELLW 64

typedef float f32x4 __attribute__((ext_vector_type(4)));
typedef short short8 __attribute__((ext_vector_type(8)));

__device__ __forceinline__ unsigned short f2bf(float f) {
    unsigned int x = __float_as_uint(f);
    return (unsigned short)((x + 0x7FFFu + ((x >> 16) & 1u)) >> 16);  // RNE
}

// ---------------- init: cur = 0 (ELL cursors), stats = 0 ----------------
__global__ void init_kernel(int* __restrict__ cur, float* __restrict__ stats) {
    int i = blockIdx.x * blockDim.x + threadIdx.x;
    if (i < N_NODES) cur[i] = 0;
    if (i < 4 * D) stats[i] = 0.0f;
}

// ---------------- transpose + bf16-cast both weight matrices ----------------
__global__ void prep_kernel(const float* __restrict__ W1, const float* __restrict__ W2,
                            unsigned short* __restrict__ WT1, unsigned short* __restrict__ WT2) {
    int idx = blockIdx.x * blockDim.x + threadIdx.x;
    if (idx >= D * D) return;
    int col = idx >> 7, k = idx & 127;
    WT1[col * D + k] = f2bf(W1[k * D + col]);
    WT2[col * D + k] = f2bf(W2[k * D + col]);
}

// ---------------- build ELL adjacency: dst -> list of src (int) ----------------
__global__ void scatter_kernel(const int* __restrict__ srcI, const int* __restrict__ dstI,
                               int* __restrict__ cur, int* __restrict__ ell) {
    int e = blockIdx.x * blockDim.x + threadIdx.x;
    if (e >= N_EDGES) return;
    int d = dstI[e];
    int pos = atomicAdd(&cur[d], 1);
    if (pos < ELLW) ell[(size_t)d * ELLW + pos] = srcI[e];
}

// ---------------- dinv = rsqrt(in_degree + 1)  (self-loop) ----------------
__global__ void dinv_kernel(const int* __restrict__ cur, float* __restrict__ dinv) {
    int i = blockIdx.x * blockDim.x + threadIdx.x;
    if (i < N_NODES) dinv[i] = rsqrtf((float)cur[i] + 1.0f);
}

// ---------------- weight-stationary MFMA GEMM ----------------
// WT (128x128 bf16, 32KB) fully resident in VGPRs per wave: b[8][4] short8 = 128 VGPR.
// Grid-stride over 16-row tiles; per tile: 8 A-loads, 32 bf16 converts, 32 MFMAs, C store.
// BN applied in f32 before convert; col stats fused via LDS.
template<bool BN, bool HAS_BIAS, bool STATS>
__global__ __launch_bounds__(256, 2) void gemm_ws_kernel(
    const float* __restrict__ A, const unsigned short* __restrict__ WT,
    const float* __restrict__ bn_sum, const float* __restrict__ bn_sq,
    const float* __restrict__ bn_gamma, const float* __restrict__ bn_beta,
    const float* __restrict__ out_bias, float* __restrict__ C, int M,
    float* __restrict__ sum_out, float* __restrict__ sq_out)
{
    __shared__ __align__(16) float scs[D];
    __shared__ __align__(16) float bis[D];
    __shared__ float ssum[D];
    __shared__ float ssq[D];

    const int tid  = threadIdx.x;
    const int lane = tid & 63;
    const int w    = tid >> 6;
    const int l15  = lane & 15;
    const int lg   = lane >> 4;

    if (BN) {
        if (tid < D) {
            const float inv_n = 1.0f / (float)N_NODES;
            float mean = bn_sum[tid] * inv_n;
            float var  = bn_sq[tid] * inv_n - mean * mean;
            float rstd = rsqrtf(var + BN_EPS);
            float sc = bn_gamma[tid] * rstd;
            scs[tid] = sc;
            bis[tid] = bn_beta[tid] - mean * sc;
        }
    }
    if (STATS) {
        if (tid < D) { ssum[tid] = 0.f; ssq[tid] = 0.f; }
    }
    if (BN || STATS) __syncthreads();

    // B fragments: one-time load, stays in registers for the whole kernel
    short8 b[8][4];
    #pragma unroll
    for (int ct = 0; ct < 8; ++ct)
        #pragma unroll
        for (int ks = 0; ks < 4; ++ks)
            b[ct][ks] = *(const short8*)&WT[(size_t)(ct * 16 + l15) * D + ks * 32 + lg * 8];

    float ob[8];
    #pragma unroll
    for (int ct = 0; ct < 8; ++ct) ob[ct] = HAS_BIAS ? out_bias[ct * 16 + l15] : 0.f;

    float psum[8], psq[8];
    #pragma unroll
    for (int ct = 0; ct < 8; ++ct) { psum[ct] = 0.f; psq[ct] = 0.f; }

    const int nt = (M + 15) / 16;   // 3125 row tiles
    for (int t = blockIdx.x * 4 + w; t < nt; t += gridDim.x * 4) {
        int ar = t * 16 + l15; if (ar > M - 1) ar = M - 1;
        short8 af[4];
        #pragma unroll
        for (int ks = 0; ks < 4; ++ks) {
            const int kb = ks * 32 + lg * 8;
            const float* ap = &A[(size_t)ar * D + kb];
            float4 v0 = *(const float4*)ap;
            float4 v1 = *(const float4*)(ap + 4);
            float vv[8] = {v0.x, v0.y, v0.z, v0.w, v1.x, v1.y, v1.z, v1.w};
            short8 a8;
            #pragma unroll
            for (int j = 0; j < 8; ++j) {
                float f = vv[j];
                if (BN) f = fmaxf(fmaf(f, scs[kb + j], bis[kb + j]), 0.f);
                a8[j] = (short)f2bf(f);
            }
            af[ks] = a8;
        }

        f32x4 acc[8];
        #pragma unroll
        for (int ct = 0; ct < 8; ++ct) acc[ct] = (f32x4){0.f, 0.f, 0.f, 0.f};
        #pragma unroll
        for (int ks = 0; ks < 4; ++ks)
            #pragma unroll
            for (int ct = 0; ct < 8; ++ct)
                acc[ct] = __builtin_amdgcn_mfma_f32_16x16x32_bf16(af[ks], b[ct][ks], acc[ct], 0, 0, 0);

        // C/D layout: col = ct*16 + l15, row = t*16 + lg*4 + j
        const int rb2 = t * 16 + lg * 4;
        #pragma unroll
        for (int j = 0; j < 4; ++j) {
            const int row = rb2 + j;
            if (row < M) {
                #pragma unroll
                for (int ct = 0; ct < 8; ++ct) {
                    float o = acc[ct][j] + ob[ct];
                    C[(size_t)row * D + ct * 16 + l15] = o;
                    if (STATS) { psum[ct] += o; psq[ct] = fmaf(o, o, psq[ct]); }
                }
            }
        }
    }

    if (STATS) {
        #pragma unroll
        for (int ct = 0; ct < 8; ++ct) {
            atomicAdd(&ssum[ct * 16 + l15], psum[ct]);
            atomicAdd(&ssq[ct * 16 + l15], psq[ct]);
        }
        __syncthreads();
        if (tid < D) {
            unsafeAtomicAdd(&sum_out[tid], ssum[tid]);
            unsafeAtomicAdd(&sq_out[tid], ssq[tid]);
        }
    }
}

// ---------------- gather: TWO nodes per wave (interleaved) for 2x memory-level parallelism
//   lane l covers cols {2l,2l+1}; edge idx/weights lane-loaded once, shfl-broadcast.
__global__ __launch_bounds__(256) void gather_kernel(
    const int* __restrict__ ell, const int* __restrict__ cnt,
    const float* __restrict__ dinv, const float* __restrict__ h2,
    const float* __restrict__ b_conv, float* __restrict__ outpre,
    float* __restrict__ sum_out, float* __restrict__ sq_out)
{
    const int lane = threadIdx.x & 63;
    const int wid  = threadIdx.x >> 6;
    const int col  = lane * 2;
    const float2 bc = *(const float2*)&b_conv[col];
    float2 sum = make_float2(0.f, 0.f);
    float2 sq  = make_float2(0.f, 0.f);

    for (int d0 = blockIdx.x * 8 + wid * 2; d0 < N_NODES; d0 += gridDim.x * 8) {
        const int d1 = d0 + 1;   // d0 always even and <= 49998, so d1 < N_NODES
        int cA = cnt[d0]; if (cA > ELLW) cA = ELLW;
        int cB = cnt[d1]; if (cB > ELLW) cB = ELLW;
        const float ddA = dinv[d0];
        const float ddB = dinv[d1];
        float2 hvA = *(const float2*)&h2[(size_t)d0 * D + col];
        float2 hvB = *(const float2*)&h2[(size_t)d1 * D + col];
        float2 accA, accB;
        accA.x = ddA * hvA.x; accA.y = ddA * hvA.y;
        accB.x = ddB * hvB.x; accB.y = ddB * hvB.y;

        int slA = 0, slB = 0;
        float wlA = 0.f, wlB = 0.f;
        if (lane < cA) { slA = ell[(size_t)d0 * ELLW + lane]; wlA = dinv[slA]; }
        if (lane < cB) { slB = ell[(size_t)d1 * ELLW + lane]; wlB = dinv[slB]; }

        const int cmin = cA < cB ? cA : cB;
        int j = 0;
        for (; j + 2 <= cmin; j += 2) {
            int sA0 = __shfl(slA, j); int sA1 = __shfl(slA, j + 1);
            int sB0 = __shfl(slB, j); int sB1 = __shfl(slB, j + 1);
            float wA0 = __shfl(wlA, j); float wA1 = __shfl(wlA, j + 1);
            float wB0 = __shfl(wlB, j); float wB1 = __shfl(wlB, j + 1);
            float2 vA0 = *(const float2*)&h2[(size_t)sA0 * D + col];
            float2 vA1 = *(const float2*)&h2[(size_t)sA1 * D + col];
            float2 vB0 = *(const float2*)&h2[(size_t)sB0 * D + col];
            float2 vB1 = *(const float2*)&h2[(size_t)sB1 * D + col];
            accA.x += wA0 * vA0.x + wA1 * vA1.x;
            accA.y += wA0 * vA0.y + wA1 * vA1.y;
            accB.x += wB0 * vB0.x + wB1 * vB1.x;
            accB.y += wB0 * vB0.y + wB1 * vB1.y;
        }
        int jA = j, jB = j;
        for (; jA + 2 <= cA; jA += 2) {
            int s0 = __shfl(slA, jA); int s1 = __shfl(slA, jA + 1);
            float w0 = __shfl(wlA, jA); float w1 = __shfl(wlA, jA + 1);
            float2 v0 = *(const float2*)&h2[(size_t)s0 * D + col];
            float2 v1 = *(const float2*)&h2[(size_t)s1 * D + col];
            accA.x += w0 * v0.x + w1 * v1.x;
            accA.y += w0 * v0.y + w1 * v1.y;
        }
        if (jA < cA) {
            int s = __shfl(slA, jA);
            float ww = __shfl(wlA, jA);
            float2 v = *(const float2*)&h2[(size_t)s * D + col];
            accA.x = fmaf(ww, v.x, accA.x);
            accA.y = fmaf(ww, v.y, accA.y);
        }
        for (; jB + 2 <= cB; jB += 2) {
            int s0 = __shfl(slB, jB); int s1 = __shfl(slB, jB + 1);
            float w0 = __shfl(wlB, jB); float w1 = __shfl(wlB, jB + 1);
            float2 v0 = *(const float2*)&h2[(size_t)s0 * D + col];
            float2 v1 = *(const float2*)&h2[(size_t)s1 * D + col];
            accB.x += w0 * v0.x + w1 * v1.x;
            accB.y += w0 * v0.y + w1 * v1.y;
        }
        if (jB < cB) {
            int s = __shfl(slB, jB);
            float ww = __shfl(wlB, jB);
            float2 v = *(const float2*)&h2[(size_t)s * D + col];
            accB.x = fmaf(ww, v.x, accB.x);
            accB.y = fmaf(ww, v.y, accB.y);
        }

        float2 oA, oB;
        oA.x = fmaf(ddA, accA.x, bc.x);
        oA.y = fmaf(ddA, accA.y, bc.y);
        oB.x = fmaf(ddB, accB.x, bc.x);
        oB.y = fmaf(ddB, accB.y, bc.y);
        *(float2*)&outpre[(size_t)d0 * D + col] = oA;
        *(float2*)&outpre[(size_t)d1 * D + col] = oB;
        sum.x += oA.x + oB.x; sum.y += oA.y + oB.y;
        sq.x = fmaf(oA.x, oA.x, sq.x); sq.x = fmaf(oB.x, oB.x, sq.x);
        sq.y = fmaf(oA.y, oA.y, sq.y); sq.y = fmaf(oB.y, oB.y, sq.y);
    }

    __shared__ float2 sS[256];
    __shared__ float2 qS[256];
    sS[threadIdx.x] = sum; qS[threadIdx.x] = sq;
    __syncthreads();
    if (wid == 0) {
        #pragma unroll
        for (int w = 1; w < 4; ++w) {
            float2 s2 = sS[w * 64 + lane];
            float2 q2 = qS[w * 64 + lane];
            sum.x += s2.x; sum.y += s2.y;
            sq.x += q2.x; sq.y += q2.y;
        }
        unsafeAtomicAdd(&sum_out[col + 0], sum.x);
        unsafeAtomicAdd(&sum_out[col + 1], sum.y);
        unsafeAtomicAdd(&sq_out[col + 0], sq.x);
        unsafeAtomicAdd(&sq_out[col + 1], sq.y);
    }
}

// ---------------- final: out = relu(out*scale2 + bias2), scale/bias from raw stats ----------------
__global__ void final_kernel(float* __restrict__ out,
        const float* __restrict__ s_sum, const float* __restrict__ s_sq,
        const float* __restrict__ gamma, const float* __restrict__ beta) {
    __shared__ __align__(16) float scs[D];
    __shared__ __align__(16) float bis[D];
    const int tid = threadIdx.x;
    if (tid < D) {
        const float inv_n = 1.0f / (float)N_NODES;
        float mean = s_sum[tid] * inv_n;
        float var  = s_sq[tid] * inv_n - mean * mean;
        float rstd = rsqrtf(var + BN_EPS);
        float sc = gamma[tid] * rstd;
        scs[tid] = sc;
        bis[tid] = beta[tid] - mean * sc;
    }
    __syncthreads();
    const int t = blockIdx.x * blockDim.x + tid;
    const int c4 = t & 31;
    float4 sc = *(const float4*)&scs[c4 * 4];
    float4 bi = *(const float4*)&bis[c4 * 4];
    const int total = N_NODES * D / 4;
    const int stride = gridDim.x * blockDim.x;
    for (int i = t; i < total; i += stride) {
        float4 v = ((const float4*)out)[i];
        v.x = fmaxf(fmaf(v.x, sc.x, bi.x), 0.f);
        v.y = fmaxf(fmaf(v.y, sc.y, bi.y), 0.f);
        v.z = fmaxf(fmaf(v.z, sc.z, bi.z), 0.f);
        v.w = fmaxf(fmaf(v.w, sc.w, bi.w), 0.f);
        ((float4*)out)[i] = v;
    }
}

extern "C" void kernel_launch(void* const* d_in, const int* in_sizes, int n_in,
                              void* d_out, int out_size, void* d_ws, size_t ws_size,
                              hipStream_t stream) {
    const float* x      = (const float*)d_in[0];
    const int*   edge   = (const int*)d_in[1];      // [2][N_EDGES], row0=src, row1=dst
    const float* W_mlp  = (const float*)d_in[2];
    const float* b_mlp  = (const float*)d_in[3];
    const float* gamma1 = (const float*)d_in[4];
    const float* beta1  = (const float*)d_in[5];
    const float* W_conv = (const float*)d_in[6];
    const float* b_conv = (const float*)d_in[7];
    const float* gamma2 = (const float*)d_in[8];
    const float* beta2  = (const float*)d_in[9];
    float* out = (float*)d_out;

    float* ws = (float*)d_ws;
    float* h1   = ws;                                  // N*D floats (25.6 MB)
    float* h2   = ws + (size_t)N_NODES * D;            // N*D floats
    int*   ell  = (int*)h1;                            // alias: h1 dead after gemm2 (12.8MB)
    float* extra = ws + 2 * (size_t)N_NODES * D;
    int*   cur  = (int*)extra;                         // N ints (ELL cursors / in-degree)
    float* dinv = extra + N_NODES;                     // N floats
    float* stats = extra + 2 * N_NODES;                // 4*D
    float* sum1 = stats;         float* sq1 = stats + D;
    float* sum2 = stats + 2 * D; float* sq2 = stats + 3 * D;
    unsigned short* WT1 = (unsigned short*)(stats + 4 * D);   // 128*128 bf16
    unsigned short* WT2 = WT1 + D * D;

    const int* srcI = edge;
    const int* dstI = edge + N_EDGES;

    init_kernel<<<(N_NODES + 255) / 256, 256, 0, stream>>>(cur, stats);
    prep_kernel<<<(D * D + 255) / 256, 256, 0, stream>>>(W_mlp, W_conv, WT1, WT2);

    gemm_ws_kernel<false, true, true><<<392, 256, 0, stream>>>(
        x, WT1, nullptr, nullptr, nullptr, nullptr, b_mlp, h1, N_NODES, sum1, sq1);

    gemm_ws_kernel<true, false, false><<<392, 256, 0, stream>>>(
        h1, WT2, sum1, sq1, gamma1, beta1, nullptr, h2, N_NODES, nullptr, nullptr);

    // h1 is dead now: build src ELL in its place
    scatter_kernel<<<(N_EDGES + 255) / 256, 256, 0, stream>>>(srcI, dstI, cur, ell);
    dinv_kernel<<<(N_NODES + 255) / 256, 256, 0, stream>>>(cur, dinv);

    gather_kernel<<<1024, 256, 0, stream>>>(ell, cur, dinv, h2, b_conv, out, sum2, sq2);

    final_kernel<<<2048, 256, 0, stream>>>(out, sum2, sq2, gamma2, beta2);
}

// Round 10
// 256.706 us; speedup vs baseline: 1.2466x; 1.0526x over previous
//
#include <hip/hip_runtime.h>
#include <math.h>

#define N_NODES 50000
#define N_EDGES 600000
#define D 128
#define BN_EPS 1e-5f
#define ELLW 64

typedef float f32x4 __attribute__((ext_vector_type(4)));
typedef short short8 __attribute__((ext_vector_type(8)));

__device__ __forceinline__ unsigned short f2bf(float f) {
    unsigned int x = __float_as_uint(f);
    return (unsigned short)((x + 0x7FFFu + ((x >> 16) & 1u)) >> 16);  // RNE
}

// ---------------- init: cur = 0 (ELL cursors), stats = 0 ----------------
__global__ void init_kernel(int* __restrict__ cur, float* __restrict__ stats) {
    int i = blockIdx.x * blockDim.x + threadIdx.x;
    if (i < N_NODES) cur[i] = 0;
    if (i < 4 * D) stats[i] = 0.0f;
}

// ---------------- transpose + bf16-cast both weight matrices ----------------
__global__ void prep_kernel(const float* __restrict__ W1, const float* __restrict__ W2,
                            unsigned short* __restrict__ WT1, unsigned short* __restrict__ WT2) {
    int idx = blockIdx.x * blockDim.x + threadIdx.x;
    if (idx >= D * D) return;
    int col = idx >> 7, k = idx & 127;
    WT1[col * D + k] = f2bf(W1[k * D + col]);
    WT2[col * D + k] = f2bf(W2[k * D + col]);
}

// ---------------- build ELL adjacency: dst -> list of src (int) ----------------
__global__ void scatter_kernel(const int* __restrict__ srcI, const int* __restrict__ dstI,
                               int* __restrict__ cur, int* __restrict__ ell) {
    int e = blockIdx.x * blockDim.x + threadIdx.x;
    if (e >= N_EDGES) return;
    int d = dstI[e];
    int pos = atomicAdd(&cur[d], 1);
    if (pos < ELLW) ell[(size_t)d * ELLW + pos] = srcI[e];
}

// ---------------- dinv = rsqrt(in_degree + 1)  (self-loop) ----------------
__global__ void dinv_kernel(const int* __restrict__ cur, float* __restrict__ dinv) {
    int i = blockIdx.x * blockDim.x + threadIdx.x;
    if (i < N_NODES) dinv[i] = rsqrtf((float)cur[i] + 1.0f);
}

// ---------------- weight-stationary MFMA GEMM ----------------
// WT (128x128 bf16, 32KB) VGPR-resident per wave. Grid-stride over 16-row tiles.
// OUT_BF16: write C as bf16 (for h2, halves gather traffic).
template<bool BN, bool HAS_BIAS, bool STATS, bool OUT_BF16>
__global__ __launch_bounds__(256, 2) void gemm_ws_kernel(
    const float* __restrict__ A, const unsigned short* __restrict__ WT,
    const float* __restrict__ bn_sum, const float* __restrict__ bn_sq,
    const float* __restrict__ bn_gamma, const float* __restrict__ bn_beta,
    const float* __restrict__ out_bias, float* __restrict__ C,
    unsigned short* __restrict__ Cb, int M,
    float* __restrict__ sum_out, float* __restrict__ sq_out)
{
    __shared__ __align__(16) float scs[D];
    __shared__ __align__(16) float bis[D];
    __shared__ float ssum[D];
    __shared__ float ssq[D];

    const int tid  = threadIdx.x;
    const int lane = tid & 63;
    const int w    = tid >> 6;
    const int l15  = lane & 15;
    const int lg   = lane >> 4;

    if (BN) {
        if (tid < D) {
            const float inv_n = 1.0f / (float)N_NODES;
            float mean = bn_sum[tid] * inv_n;
            float var  = bn_sq[tid] * inv_n - mean * mean;
            float rstd = rsqrtf(var + BN_EPS);
            float sc = bn_gamma[tid] * rstd;
            scs[tid] = sc;
            bis[tid] = bn_beta[tid] - mean * sc;
        }
    }
    if (STATS) {
        if (tid < D) { ssum[tid] = 0.f; ssq[tid] = 0.f; }
    }
    if (BN || STATS) __syncthreads();

    // B fragments: one-time load, stays in registers for the whole kernel
    short8 b[8][4];
    #pragma unroll
    for (int ct = 0; ct < 8; ++ct)
        #pragma unroll
        for (int ks = 0; ks < 4; ++ks)
            b[ct][ks] = *(const short8*)&WT[(size_t)(ct * 16 + l15) * D + ks * 32 + lg * 8];

    float ob[8];
    #pragma unroll
    for (int ct = 0; ct < 8; ++ct) ob[ct] = HAS_BIAS ? out_bias[ct * 16 + l15] : 0.f;

    float psum[8], psq[8];
    #pragma unroll
    for (int ct = 0; ct < 8; ++ct) { psum[ct] = 0.f; psq[ct] = 0.f; }

    const int nt = (M + 15) / 16;   // 3125 row tiles
    for (int t = blockIdx.x * 4 + w; t < nt; t += gridDim.x * 4) {
        int ar = t * 16 + l15; if (ar > M - 1) ar = M - 1;
        short8 af[4];
        #pragma unroll
        for (int ks = 0; ks < 4; ++ks) {
            const int kb = ks * 32 + lg * 8;
            const float* ap = &A[(size_t)ar * D + kb];
            float4 v0 = *(const float4*)ap;
            float4 v1 = *(const float4*)(ap + 4);
            float vv[8] = {v0.x, v0.y, v0.z, v0.w, v1.x, v1.y, v1.z, v1.w};
            short8 a8;
            #pragma unroll
            for (int j = 0; j < 8; ++j) {
                float f = vv[j];
                if (BN) f = fmaxf(fmaf(f, scs[kb + j], bis[kb + j]), 0.f);
                a8[j] = (short)f2bf(f);
            }
            af[ks] = a8;
        }

        f32x4 acc[8];
        #pragma unroll
        for (int ct = 0; ct < 8; ++ct) acc[ct] = (f32x4){0.f, 0.f, 0.f, 0.f};
        #pragma unroll
        for (int ks = 0; ks < 4; ++ks)
            #pragma unroll
            for (int ct = 0; ct < 8; ++ct)
                acc[ct] = __builtin_amdgcn_mfma_f32_16x16x32_bf16(af[ks], b[ct][ks], acc[ct], 0, 0, 0);

        // C/D layout: col = ct*16 + l15, row = t*16 + lg*4 + j
        const int rb2 = t * 16 + lg * 4;
        #pragma unroll
        for (int j = 0; j < 4; ++j) {
            const int row = rb2 + j;
            if (row < M) {
                #pragma unroll
                for (int ct = 0; ct < 8; ++ct) {
                    float o = acc[ct][j] + ob[ct];
                    if (OUT_BF16) Cb[(size_t)row * D + ct * 16 + l15] = f2bf(o);
                    else          C[(size_t)row * D + ct * 16 + l15] = o;
                    if (STATS) { psum[ct] += o; psq[ct] = fmaf(o, o, psq[ct]); }
                }
            }
        }
    }

    if (STATS) {
        #pragma unroll
        for (int ct = 0; ct < 8; ++ct) {
            atomicAdd(&ssum[ct * 16 + l15], psum[ct]);
            atomicAdd(&ssq[ct * 16 + l15], psq[ct]);
        }
        __syncthreads();
        if (tid < D) {
            unsafeAtomicAdd(&sum_out[tid], ssum[tid]);
            unsafeAtomicAdd(&sq_out[tid], ssq[tid]);
        }
    }
}

// bf16-pair load helper: word -> two floats
__device__ __forceinline__ void bfp(unsigned pv, float& fx, float& fy) {
    fx = __uint_as_float(pv << 16);
    fy = __uint_as_float(pv & 0xFFFF0000u);
}

// ---------------- gather over bf16 h2: TWO nodes per wave, 4-edge unroll ----------------
__global__ __launch_bounds__(256) void gather_kernel(
    const int* __restrict__ ell, const int* __restrict__ cnt,
    const float* __restrict__ dinv, const unsigned short* __restrict__ h2b,
    const float* __restrict__ b_conv, float* __restrict__ outpre,
    float* __restrict__ sum_out, float* __restrict__ sq_out)
{
    const int lane = threadIdx.x & 63;
    const int wid  = threadIdx.x >> 6;
    const int col  = lane * 2;
    const float2 bc = *(const float2*)&b_conv[col];
    float2 sum = make_float2(0.f, 0.f);
    float2 sq  = make_float2(0.f, 0.f);

    for (int d0 = blockIdx.x * 8 + wid * 2; d0 < N_NODES; d0 += gridDim.x * 8) {
        const int d1 = d0 + 1;
        int cA = cnt[d0]; if (cA > ELLW) cA = ELLW;
        int cB = cnt[d1]; if (cB > ELLW) cB = ELLW;
        const float ddA = dinv[d0];
        const float ddB = dinv[d1];
        float hAx, hAy, hBx, hBy;
        bfp(*(const unsigned*)&h2b[(size_t)d0 * D + col], hAx, hAy);
        bfp(*(const unsigned*)&h2b[(size_t)d1 * D + col], hBx, hBy);
        float2 accA, accB;
        accA.x = ddA * hAx; accA.y = ddA * hAy;
        accB.x = ddB * hBx; accB.y = ddB * hBy;

        int slA = 0, slB = 0;
        float wlA = 0.f, wlB = 0.f;
        if (lane < cA) { slA = ell[(size_t)d0 * ELLW + lane]; wlA = dinv[slA]; }
        if (lane < cB) { slB = ell[(size_t)d1 * ELLW + lane]; wlB = dinv[slB]; }

        const int cmin = cA < cB ? cA : cB;
        int j = 0;
        for (; j + 4 <= cmin; j += 4) {
            unsigned pA[4], pB[4];
            float wA[4], wB[4];
            #pragma unroll
            for (int u = 0; u < 4; ++u) {
                int sA = __shfl(slA, j + u);
                int sB = __shfl(slB, j + u);
                wA[u] = __shfl(wlA, j + u);
                wB[u] = __shfl(wlB, j + u);
                pA[u] = *(const unsigned*)&h2b[(size_t)sA * D + col];
                pB[u] = *(const unsigned*)&h2b[(size_t)sB * D + col];
            }
            #pragma unroll
            for (int u = 0; u < 4; ++u) {
                float ax, ay, bx, by;
                bfp(pA[u], ax, ay);
                bfp(pB[u], bx, by);
                accA.x = fmaf(wA[u], ax, accA.x);
                accA.y = fmaf(wA[u], ay, accA.y);
                accB.x = fmaf(wB[u], bx, accB.x);
                accB.y = fmaf(wB[u], by, accB.y);
            }
        }
        int jA = j, jB = j;
        for (; jA < cA; ++jA) {
            int s = __shfl(slA, jA);
            float ww = __shfl(wlA, jA);
            float ax, ay;
            bfp(*(const unsigned*)&h2b[(size_t)s * D + col], ax, ay);
            accA.x = fmaf(ww, ax, accA.x);
            accA.y = fmaf(ww, ay, accA.y);
        }
        for (; jB < cB; ++jB) {
            int s = __shfl(slB, jB);
            float ww = __shfl(wlB, jB);
            float bx, by;
            bfp(*(const unsigned*)&h2b[(size_t)s * D + col], bx, by);
            accB.x = fmaf(ww, bx, accB.x);
            accB.y = fmaf(ww, by, accB.y);
        }

        float2 oA, oB;
        oA.x = fmaf(ddA, accA.x, bc.x);
        oA.y = fmaf(ddA, accA.y, bc.y);
        oB.x = fmaf(ddB, accB.x, bc.x);
        oB.y = fmaf(ddB, accB.y, bc.y);
        *(float2*)&outpre[(size_t)d0 * D + col] = oA;
        *(float2*)&outpre[(size_t)d1 * D + col] = oB;
        sum.x += oA.x + oB.x; sum.y += oA.y + oB.y;
        sq.x = fmaf(oA.x, oA.x, sq.x); sq.x = fmaf(oB.x, oB.x, sq.x);
        sq.y = fmaf(oA.y, oA.y, sq.y); sq.y = fmaf(oB.y, oB.y, sq.y);
    }

    __shared__ float2 sS[256];
    __shared__ float2 qS[256];
    sS[threadIdx.x] = sum; qS[threadIdx.x] = sq;
    __syncthreads();
    if (wid == 0) {
        #pragma unroll
        for (int w = 1; w < 4; ++w) {
            float2 s2 = sS[w * 64 + lane];
            float2 q2 = qS[w * 64 + lane];
            sum.x += s2.x; sum.y += s2.y;
            sq.x += q2.x; sq.y += q2.y;
        }
        unsafeAtomicAdd(&sum_out[col + 0], sum.x);
        unsafeAtomicAdd(&sum_out[col + 1], sum.y);
        unsafeAtomicAdd(&sq_out[col + 0], sq.x);
        unsafeAtomicAdd(&sq_out[col + 1], sq.y);
    }
}

// ---------------- final: out = relu(out*scale2 + bias2), scale/bias from raw stats ----------------
__global__ void final_kernel(float* __restrict__ out,
        const float* __restrict__ s_sum, const float* __restrict__ s_sq,
        const float* __restrict__ gamma, const float* __restrict__ beta) {
    __shared__ __align__(16) float scs[D];
    __shared__ __align__(16) float bis[D];
    const int tid = threadIdx.x;
    if (tid < D) {
        const float inv_n = 1.0f / (float)N_NODES;
        float mean = s_sum[tid] * inv_n;
        float var  = s_sq[tid] * inv_n - mean * mean;
        float rstd = rsqrtf(var + BN_EPS);
        float sc = gamma[tid] * rstd;
        scs[tid] = sc;
        bis[tid] = beta[tid] - mean * sc;
    }
    __syncthreads();
    const int t = blockIdx.x * blockDim.x + tid;
    const int c4 = t & 31;
    float4 sc = *(const float4*)&scs[c4 * 4];
    float4 bi = *(const float4*)&bis[c4 * 4];
    const int total = N_NODES * D / 4;
    const int stride = gridDim.x * blockDim.x;
    for (int i = t; i < total; i += stride) {
        float4 v = ((const float4*)out)[i];
        v.x = fmaxf(fmaf(v.x, sc.x, bi.x), 0.f);
        v.y = fmaxf(fmaf(v.y, sc.y, bi.y), 0.f);
        v.z = fmaxf(fmaf(v.z, sc.z, bi.z), 0.f);
        v.w = fmaxf(fmaf(v.w, sc.w, bi.w), 0.f);
        ((float4*)out)[i] = v;
    }
}

extern "C" void kernel_launch(void* const* d_in, const int* in_sizes, int n_in,
                              void* d_out, int out_size, void* d_ws, size_t ws_size,
                              hipStream_t stream) {
    const float* x      = (const float*)d_in[0];
    const int*   edge   = (const int*)d_in[1];      // [2][N_EDGES], row0=src, row1=dst
    const float* W_mlp  = (const float*)d_in[2];
    const float* b_mlp  = (const float*)d_in[3];
    const float* gamma1 = (const float*)d_in[4];
    const float* beta1  = (const float*)d_in[5];
    const float* W_conv = (const float*)d_in[6];
    const float* b_conv = (const float*)d_in[7];
    const float* gamma2 = (const float*)d_in[8];
    const float* beta2  = (const float*)d_in[9];
    float* out = (float*)d_out;

    float* ws = (float*)d_ws;
    float* h1   = ws;                                  // N*D floats (25.6 MB)
    unsigned short* h2b = (unsigned short*)(ws + (size_t)N_NODES * D);  // N*D bf16 (12.8 MB)
    int*   ell  = (int*)h1;                            // alias: h1 dead after gemm2 (12.8MB)
    float* extra = ws + 2 * (size_t)N_NODES * D;
    int*   cur  = (int*)extra;                         // N ints (ELL cursors / in-degree)
    float* dinv = extra + N_NODES;                     // N floats
    float* stats = extra + 2 * N_NODES;                // 4*D
    float* sum1 = stats;         float* sq1 = stats + D;
    float* sum2 = stats + 2 * D; float* sq2 = stats + 3 * D;
    unsigned short* WT1 = (unsigned short*)(stats + 4 * D);   // 128*128 bf16
    unsigned short* WT2 = WT1 + D * D;

    const int* srcI = edge;
    const int* dstI = edge + N_EDGES;

    init_kernel<<<(N_NODES + 255) / 256, 256, 0, stream>>>(cur, stats);
    prep_kernel<<<(D * D + 255) / 256, 256, 0, stream>>>(W_mlp, W_conv, WT1, WT2);

    gemm_ws_kernel<false, true, true, false><<<392, 256, 0, stream>>>(
        x, WT1, nullptr, nullptr, nullptr, nullptr, b_mlp, h1, nullptr, N_NODES, sum1, sq1);

    gemm_ws_kernel<true, false, false, true><<<392, 256, 0, stream>>>(
        h1, WT2, sum1, sq1, gamma1, beta1, nullptr, nullptr, h2b, N_NODES, nullptr, nullptr);

    // h1 is dead now: build src ELL in its place
    scatter_kernel<<<(N_EDGES + 255) / 256, 256, 0, stream>>>(srcI, dstI, cur, ell);
    dinv_kernel<<<(N_NODES + 255) / 256, 256, 0, stream>>>(cur, dinv);

    gather_kernel<<<1024, 256, 0, stream>>>(ell, cur, dinv, h2b, b_conv, out, sum2, sq2);

    final_kernel<<<2048, 256, 0, stream>>>(out, sum2, sq2, gamma2, beta2);
}